// Round 16
// baseline (213.125 us; speedup 1.0000x reference)
//
#include <hip/hip_runtime.h>
#include <hip/hip_bf16.h>
#include <math.h>

#define N_NODES 100000
#define N_EDGES 3200000
#define NB 16           // nodes per block-iteration (node phase)
#define EPSV 1e-8f

#define NBUCK 782                   // buckets of 128 nodes
#define NCHUNK 2000                 // edge chunks
#define CHUNK_E 1600                // edges per chunk
#define HALF_E 800                  // staging half

#define CE 256                      // reduce: entries per staging chunk
#define RS 264                      // reduce: staging row stride (u16)

typedef __attribute__((ext_vector_type(8))) short short8;
typedef __attribute__((ext_vector_type(4))) float f32x4;

static __device__ __forceinline__ unsigned short f2bf(float x) {
  union { float f; unsigned int u; } c; c.f = x;
  unsigned int r = c.u + 0x7fff + ((c.u >> 16) & 1);   // RNE
  return (unsigned short)(r >> 16);
}
static __device__ __forceinline__ unsigned short f2bf_bits(unsigned int u) {
  unsigned int r = u + 0x7fff + ((u >> 16) & 1);       // RNE on raw bits
  return (unsigned short)(r >> 16);
}

// ------- A: per-chunk histogram + in-register bucket scan -> hist, lscan ----
__global__ __launch_bounds__(256) void hist_kernel(const int* __restrict__ row,
                                                   unsigned short* __restrict__ hist,
                                                   unsigned short* __restrict__ lscan) {
  __shared__ int lh[NBUCK];
  __shared__ int wtot[4];
  for (int i = threadIdx.x; i < NBUCK; i += 256) lh[i] = 0;
  __syncthreads();
  const int c = blockIdx.x;
  const int e1 = c * CHUNK_E + CHUNK_E;
  for (int e = c * CHUNK_E + threadIdx.x; e < e1; e += 256)
    atomicAdd(&lh[row[e] >> 7], 1);
  __syncthreads();
  // shuffle scan: thread t owns buckets 4t..4t+3
  const int t = threadIdx.x, lane = t & 63, wid = t >> 6;
  const int b0 = t * 4;
  int h[4];
#pragma unroll
  for (int j = 0; j < 4; ++j) h[j] = (b0 + j < NBUCK) ? lh[b0 + j] : 0;
  int s = h[0] + h[1] + h[2] + h[3];
  int incl = s;
#pragma unroll
  for (int d = 1; d < 64; d <<= 1) {
    int o = __shfl_up(incl, d);
    if (lane >= d) incl += o;
  }
  if (lane == 63) wtot[wid] = incl;
  __syncthreads();
  int pre = incl - s;
  for (int w = 0; w < wid; ++w) pre += wtot[w];
#pragma unroll
  for (int j = 0; j < 4; ++j) {
    if (b0 + j < NBUCK) {
      hist [(size_t)c * NBUCK + b0 + j] = (unsigned short)h[j];
      lscan[(size_t)c * NBUCK + b0 + j] = (unsigned short)pre;
    }
    pre += h[j];
  }
}

// ------- B1: in-place exclusive scan over chunks per bucket -----------------
__global__ __launch_bounds__(256) void scanc_kernel(unsigned short* __restrict__ hist,
                                                    int* __restrict__ total) {
  __shared__ int s[2][NCHUNK];
  const int b = blockIdx.x;
  const int t = threadIdx.x;
  for (int i = t; i < NCHUNK; i += 256) s[0][i] = hist[(size_t)i * NBUCK + b];
  __syncthreads();
  int src = 0;
  for (int off = 1; off < NCHUNK; off <<= 1) {
    int dst = src ^ 1;
    for (int i = t; i < NCHUNK; i += 256)
      s[dst][i] = s[src][i] + ((i >= off) ? s[src][i - off] : 0);
    __syncthreads();
    src = dst;
  }
  for (int i = t; i < NCHUNK; i += 256)
    hist[(size_t)i * NBUCK + b] = (unsigned short)((i == 0) ? 0 : s[src][i - 1]);
  if (t == 0) total[b] = s[src][NCHUNK - 1];
}

// ---------------- B2: exclusive scan over buckets ---------------------------
__global__ __launch_bounds__(256) void scanb_kernel(const int* __restrict__ total,
                                                    int* __restrict__ base) {
  __shared__ int s[2][1024];
  const int t = threadIdx.x;
  for (int i = t; i < 1024; i += 256) s[0][i] = (i < NBUCK) ? total[i] : 0;
  __syncthreads();
  int src = 0;
  for (int off = 1; off < 1024; off <<= 1) {
    int dst = src ^ 1;
    for (int i = t; i < 1024; i += 256)
      s[dst][i] = s[src][i] + ((i >= off) ? s[src][i - off] : 0);
    __syncthreads();
    src = dst;
  }
  for (int i = t; i <= NBUCK; i += 256) base[i] = (i == 0) ? 0 : s[src][i - 1];
}

// ------- C: scatter — coalesced uint4 frame reads via LDS transpose ---------
__global__ __launch_bounds__(512) void scatter_kernel(const int* __restrict__ row,
                                                      const unsigned short* __restrict__ lscan,
                                                      const unsigned short* __restrict__ cscan,
                                                      const int* __restrict__ base,
                                                      const float* __restrict__ frames,
                                                      unsigned int* __restrict__ payload) {
  __shared__ unsigned int sbuf[CHUNK_E * 5];                // 32 KB
  __shared__ unsigned int rawb[HALF_E * 9 / 2];             // 14.4 KB bf16 pairs
  __shared__ int lstart[NBUCK], loff[NBUCK], runG[NBUCK];   // 9.4 KB
  const int c = blockIdx.x, tid = threadIdx.x;

  for (int i = tid; i < NBUCK; i += 512) {
    int st = (int)lscan[(size_t)c * NBUCK + i];
    lstart[i] = st;
    loff[i] = st;
    runG[i] = base[i] + (int)cscan[(size_t)c * NBUCK + i];
  }

  const unsigned short* raw16 = (const unsigned short*)rawb;
  const int e0 = c * CHUNK_E;
  for (int h = 0; h < 2; ++h) {
    __syncthreads();   // loff ready / previous half's build done with rawb
    // stage: fully coalesced 16B loads of 800 edges' frames, cvt to bf16
    const uint4* fr4 = (const uint4*)(frames + (size_t)(e0 + h * HALF_E) * 9);
    for (int i = tid; i < HALF_E * 9 / 4; i += 512) {   // 1800 uint4
      uint4 q = fr4[i];
      rawb[i * 2]     = f2bf_bits(q.x) | ((unsigned)f2bf_bits(q.y) << 16);
      rawb[i * 2 + 1] = f2bf_bits(q.z) | ((unsigned)f2bf_bits(q.w) << 16);
    }
    __syncthreads();
    // build: 9x ds_read_u16 per edge (stride 18B, conflict-free), sort in LDS
    for (int le = tid; le < HALF_E; le += 512) {
      int e = e0 + h * HALF_E + le;
      int r = row[e];
      int bix = le * 9;
      unsigned w0 = raw16[bix + 0] | ((unsigned)raw16[bix + 1] << 16);
      unsigned w1 = raw16[bix + 2] | ((unsigned)raw16[bix + 3] << 16);
      unsigned w2 = raw16[bix + 4] | ((unsigned)raw16[bix + 5] << 16);
      unsigned w3 = raw16[bix + 6] | ((unsigned)raw16[bix + 7] << 16);
      unsigned w4 = raw16[bix + 8] | ((unsigned)(r & 127) << 16);
      int p = atomicAdd(&loff[r >> 7], 1);
      unsigned int* d = sbuf + p * 5;
      d[0] = w0; d[1] = w1; d[2] = w2; d[3] = w3; d[4] = w4;
    }
  }
  __syncthreads();

  // phase B: burst runs out; 16-lane group per run
  const int grp = tid >> 4, gl = tid & 15;
  for (int b = grp; b < NBUCK; b += 32) {
    int ls = lstart[b] * 5;
    int n5 = (loff[b] - lstart[b]) * 5;
    size_t gs = (size_t)runG[b] * 5;
    for (int d = gl; d < n5; d += 16)
      payload[gs + d] = sbuf[ls + d];
  }
}

// ------- D: per-bucket (128-node) reduce — one-hot MFMA, zero atomics -------
__global__ __launch_bounds__(256) void reduce_kernel(const unsigned int* __restrict__ payload,
                                                     const int* __restrict__ base,
                                                     float* __restrict__ acc) {
  __shared__ unsigned short stg[2][16][RS];
  const int tid = threadIdx.x;
  const int b = blockIdx.x;
  const int wid = tid >> 6, lane = tid & 63;
  const int lr = lane & 15, lk = lane >> 4;

  for (int i = tid; i < RS; i += 256) {            // count row = 1.0 bf16
    stg[0][9][i] = 0x3F80; stg[1][9][i] = 0x3F80;
  }

  const int p0 = base[b], p1 = base[b + 1];
  const int nch = (p1 - p0 + CE - 1) / CE;
  const int s0 = wid * 2;
  const unsigned na = (unsigned)((s0 << 4) | lr);       // per-lane full-id consts
  const unsigned nbod = (unsigned)(((s0 + 1) << 4) | lr);

  f32x4 c0 = {0.f, 0.f, 0.f, 0.f};
  f32x4 c1 = {0.f, 0.f, 0.f, 0.f};

  auto STAGE = [&](int c, int buf) {
    int p = p0 + c * CE + tid;
    if (p < p1) {
      const unsigned int* s = payload + (size_t)p * 5;
      unsigned int w0 = s[0], w1 = s[1], w2 = s[2], w3 = s[3], w4 = s[4];
      stg[buf][0][tid] = (unsigned short)w0;
      stg[buf][1][tid] = (unsigned short)(w0 >> 16);
      stg[buf][2][tid] = (unsigned short)w1;
      stg[buf][3][tid] = (unsigned short)(w1 >> 16);
      stg[buf][4][tid] = (unsigned short)w2;
      stg[buf][5][tid] = (unsigned short)(w2 >> 16);
      stg[buf][6][tid] = (unsigned short)w3;
      stg[buf][7][tid] = (unsigned short)(w3 >> 16);
      stg[buf][8][tid] = (unsigned short)w4;
      stg[buf][10][tid] = (unsigned short)(w4 >> 16);
    } else {
#pragma unroll
      for (int k = 0; k < 9; ++k) stg[buf][k][tid] = 0;   // keep B finite
      stg[buf][10][tid] = 0xFFFF;                         // matches no id
    }
  };

  auto COMP = [&](int buf) {
#pragma unroll
    for (int g = 0; g < 8; ++g) {
      short8 bf = *(const short8*)&stg[buf][lr][g * 32 + lk * 8];
      short8 nv = *(const short8*)&stg[buf][10][g * 32 + lk * 8]; // broadcast
      short8 a0, a1;
#pragma unroll
      for (int j = 0; j < 8; ++j) {
        unsigned nid = (unsigned short)nv[j];
        a0[j] = (short)((nid == na)   ? 0x3F80 : 0);
        a1[j] = (short)((nid == nbod) ? 0x3F80 : 0);
      }
      c0 = __builtin_amdgcn_mfma_f32_16x16x32_bf16(a0, bf, c0, 0, 0, 0);
      c1 = __builtin_amdgcn_mfma_f32_16x16x32_bf16(a1, bf, c1, 0, 0, 0);
    }
  };

  if (nch > 0) {
    STAGE(0, 0);
    __syncthreads();
    for (int c = 0; c < nch; ++c) {
      if (c + 1 < nch) STAGE(c + 1, (c + 1) & 1);  // overlap with compute
      COMP(c & 1);
      __syncthreads();
    }
  }
  // writeout: D col = comp (lr), row = lk*4+j within subtile
  const int n0 = b << 7;
  if (lr < 10) {
#pragma unroll
    for (int j = 0; j < 4; ++j) {
      int r = lk * 4 + j;
      int x0 = n0 + s0 * 16 + r;
      int x1 = n0 + (s0 + 1) * 16 + r;
      if (x0 < N_NODES) acc[(size_t)x0 * 10 + lr] = c0[j];
      if (x1 < N_NODES) acc[(size_t)x1 * 10 + lr] = c1[j];
    }
  }
}

// ---------------- prep: pre-swizzle Ws/Wg into MFMA B-fragment layout -------
__global__ __launch_bounds__(256) void prep_kernel(const float* __restrict__ Ws,
                                                   const float* __restrict__ Wg,
                                                   unsigned short* __restrict__ wsWs,
                                                   unsigned short* __restrict__ wsWg) {
  int idx = blockIdx.x * 256 + threadIdx.x;     // 80 blocks -> 20480 threads
  if (idx < 8 * 5 * 512) {                      // ((nt*5+kk)*64 + l)*8 + j
    int j = idx & 7, l = (idx >> 3) & 63, t = idx >> 9;
    int nt = t / 5, kk = t - nt * 5;
    int o = nt * 16 + (l & 15);
    int m = kk * 32 + ((l >> 4) << 3) + j;
    wsWs[idx] = (m < 153) ? f2bf(Ws[o * 153 + m]) : (unsigned short)0;
  }
  if (idx < 4 * 512) {                          // ((kk*64 + l)*8 + j)
    int j = idx & 7, l = (idx >> 3) & 63, kk = idx >> 9;
    int v = l & 15;
    int m = kk * 32 + ((l >> 4) << 3) + j;
    wsWg[idx] = f2bf(Wg[v * 128 + m]);
  }
}

// ---------------- node phase: MFMA for big matvec + gate --------------------
__global__ __launch_bounds__(256, 4) void node_kernel(
    const float* __restrict__ scalar_rep,   // [N][128]
    const float* __restrict__ vrep,         // [N][16][3]
    const float* __restrict__ Wd,           // [16][16]
    const float* __restrict__ Wf,           // [3][16]
    const float* __restrict__ bs,           // [128]
    const float* __restrict__ Wu,           // [16][16]
    const float* __restrict__ bg,           // [16]
    const unsigned short* __restrict__ wsWs,// pre-swizzled B-frags [8][5][64][8]
    const unsigned short* __restrict__ wsWg,// pre-swizzled B-frags [4][64][8]
    const float* __restrict__ acc,          // [N][10]
    float* __restrict__ out_s,              // [N][128]
    float* __restrict__ out_v) {            // [N][16][3]
  __shared__ alignas(16) unsigned short s_mergedb[16 * 168];  // bf16, pad->168
  __shared__ alignas(16) unsigned short s_sfb[16 * 136];      // bf16 silu
  __shared__ float s_vrep[16][48];
  __shared__ float s_vh[16][48];
  __shared__ float s_vdf[16][12];
  __shared__ float s_gate[16][16];
  __shared__ float s_WdT[256], s_WuT[256], s_Wf[48], s_bs[128], s_bg[16];

  const int tid = threadIdx.x;
  {
    int a = tid >> 4, b = tid & 15;
    s_WdT[b * 16 + a] = Wd[tid];
    s_WuT[b * 16 + a] = Wu[tid];
  }
  if (tid < 48) s_Wf[tid] = Wf[tid];
  if (tid < 128) s_bs[tid] = bs[tid];
  if (tid < 16) s_bg[tid] = bg[tid];
  if (tid < 240) {                       // zero merged pad cols 153..167
    int r = tid / 15, c = 153 + tid % 15;
    s_mergedb[r * 168 + c] = 0;
  }

  const int i4 = tid >> 4, j4 = tid & 15;
  const int wid = tid >> 6, lane = tid & 63;
  const int lr = lane & 15, lk = lane >> 4;

  const float4* scalar4 = (const float4*)scalar_rep;
  const float4* vrep4 = (const float4*)vrep;

  for (int g = blockIdx.x; g < N_NODES / NB; g += gridDim.x) {
    const int n0 = g * NB;
    __syncthreads();   // previous iteration consumers done
    // stage scalar_rep -> bf16 merged[.,0:128]
    for (int idx = tid; idx < 512; idx += 256) {
      float4 v = scalar4[(size_t)n0 * 32 + idx];
      int r = idx >> 5, c4 = idx & 31;
      unsigned short* d = s_mergedb + r * 168 + c4 * 4;
      d[0] = f2bf(v.x); d[1] = f2bf(v.y); d[2] = f2bf(v.z); d[3] = f2bf(v.w);
    }
    // stage vector_rep f32
    for (int idx = tid; idx < 192; idx += 256)
      ((float4*)s_vrep)[idx] = vrep4[(size_t)n0 * 12 + idx];
    __syncthreads();
    // vh + vnorm
    {
      float a0 = 0.f, a1 = 0.f, a2 = 0.f;
#pragma unroll
      for (int v = 0; v < 16; ++v) {
        float w = s_WdT[v * 16 + j4];
        a0 += s_vrep[i4][v * 3 + 0] * w;
        a1 += s_vrep[i4][v * 3 + 1] * w;
        a2 += s_vrep[i4][v * 3 + 2] * w;
      }
      s_vh[i4][j4]      = a0;
      s_vh[i4][16 + j4] = a1;
      s_vh[i4][32 + j4] = a2;
      s_mergedb[i4 * 168 + 128 + j4] = f2bf(sqrtf(a0 * a0 + a1 * a1 + a2 * a2 + EPSV));
    }
    // vdf
    if (j4 < 9) {
      int t = j4 / 3, f = j4 - t * 3;
      float a = 0.f;
#pragma unroll
      for (int v = 0; v < 16; ++v)
        a += s_vrep[i4][v * 3 + t] * s_Wf[f * 16 + v];
      s_vdf[i4][j4] = a;
    }
    __syncthreads();
    // scalar_hidden -> merged[.,144:153]
    if (j4 < 9) {
      int f = j4 / 3, s = j4 - f * 3;
      const float* a = acc + (size_t)(n0 + i4) * 10;
      float c = fmaxf(a[9], 1.0f);
      float sum = a[s * 3 + 0] * s_vdf[i4][0 + f] +
                  a[s * 3 + 1] * s_vdf[i4][3 + f] +
                  a[s * 3 + 2] * s_vdf[i4][6 + f];
      s_mergedb[i4 * 168 + 144 + j4] = f2bf(sum / c);
    }
    __syncthreads();
    // big MFMA: merged[16x160] @ WsT[160x128]; wave wid owns N-tiles 2w,2w+1
    {
      const int nt0 = wid * 2;
      short8 afrag[5];
#pragma unroll
      for (int kk = 0; kk < 5; ++kk)
        afrag[kk] = *(const short8*)(s_mergedb + lr * 168 + kk * 32 + lk * 8);
      float b0v = s_bs[nt0 * 16 + lr], b1v = s_bs[nt0 * 16 + 16 + lr];
      f32x4 acc0 = {b0v, b0v, b0v, b0v};
      f32x4 acc1 = {b1v, b1v, b1v, b1v};
#pragma unroll
      for (int kk = 0; kk < 5; ++kk) {
        short8 bf0 = *(const short8*)(wsWs + (((nt0 * 5 + kk) << 6) + lane) * 8);
        short8 bf1 = *(const short8*)(wsWs + ((((nt0 + 1) * 5 + kk) << 6) + lane) * 8);
        acc0 = __builtin_amdgcn_mfma_f32_16x16x32_bf16(afrag[kk], bf0, acc0, 0, 0, 0);
        acc1 = __builtin_amdgcn_mfma_f32_16x16x32_bf16(afrag[kk], bf1, acc1, 0, 0, 0);
      }
#pragma unroll
      for (int j = 0; j < 4; ++j) {
        int node = lk * 4 + j;
        float x0 = acc0[j];
        float sf0 = x0 / (1.0f + __expf(-x0));
        out_s[(size_t)(n0 + node) * 128 + nt0 * 16 + lr] = sf0;
        s_sfb[node * 136 + nt0 * 16 + lr] = f2bf(sf0);
        float x1 = acc1[j];
        float sf1 = x1 / (1.0f + __expf(-x1));
        out_s[(size_t)(n0 + node) * 128 + nt0 * 16 + 16 + lr] = sf1;
        s_sfb[node * 136 + nt0 * 16 + 16 + lr] = f2bf(sf1);
      }
    }
    __syncthreads();
    // gate MFMA on wave 0: sf[16x128] @ WgT[128x16]
    if (wid == 0) {
      float gb = s_bg[lr];
      f32x4 gacc = {gb, gb, gb, gb};
#pragma unroll
      for (int kk = 0; kk < 4; ++kk) {
        short8 ga = *(const short8*)(s_sfb + lr * 136 + kk * 32 + lk * 8);
        short8 gw = *(const short8*)(wsWg + (((kk << 6) + lane) * 8));
        gacc = __builtin_amdgcn_mfma_f32_16x16x32_bf16(ga, gw, gacc, 0, 0, 0);
      }
#pragma unroll
      for (int j = 0; j < 4; ++j) {
        int node = lk * 4 + j;
        s_gate[node][lr] = 1.0f / (1.0f + __expf(-gacc[j]));
      }
    }
    __syncthreads();
    // v_up + gated output
    {
      float b0 = 0.f, b1 = 0.f, b2 = 0.f;
#pragma unroll
      for (int h = 0; h < 16; ++h) {
        float w = s_WuT[h * 16 + j4];
        b0 += s_vh[i4][h]      * w;
        b1 += s_vh[i4][16 + h] * w;
        b2 += s_vh[i4][32 + h] * w;
      }
      float gt = s_gate[i4][j4];
      size_t basep = (size_t)(n0 + i4) * 48 + (size_t)j4 * 3;
      out_v[basep + 0] = b0 * gt;
      out_v[basep + 1] = b1 * gt;
      out_v[basep + 2] = b2 * gt;
    }
  }
}

extern "C" void kernel_launch(void* const* d_in, const int* in_sizes, int n_in,
                              void* d_out, int out_size, void* d_ws, size_t ws_size,
                              hipStream_t stream) {
  const float* scalar_rep = (const float*)d_in[0];
  const float* vector_rep = (const float*)d_in[1];
  const float* frames     = (const float*)d_in[2];
  const float* W_down     = (const float*)d_in[3];
  const float* W_frames   = (const float*)d_in[4];
  const float* W_scalar   = (const float*)d_in[5];
  const float* b_scalar   = (const float*)d_in[6];
  const float* W_up       = (const float*)d_in[7];
  const float* W_gate     = (const float*)d_in[8];
  const float* b_gate     = (const float*)d_in[9];
  const int*   edge_index = (const int*)d_in[10];   // [2][E], row = first E

  float* out = (float*)d_out;

  // workspace layout
  unsigned short* hist  = (unsigned short*)d_ws;            // 2000*782 u16 (becomes cscan)
  unsigned short* lscan = hist  + (size_t)NCHUNK * NBUCK;   // 2000*782 u16
  int*   total   = (int*)(lscan + (size_t)NCHUNK * NBUCK);  // 800
  int*   base    = total + 800;                             // 800
  unsigned int* payload = (unsigned int*)(base + 800);      // 3.2M * 5 dw = 64MB
  float* acc     = (float*)(payload + 16000000);            // 1M floats
  unsigned short* wsWs = (unsigned short*)(acc + 1000000);  // 20480 bf16
  unsigned short* wsWg = wsWs + 20480;                      // 2048 bf16

  prep_kernel   <<<80,     256, 0, stream>>>(W_scalar, W_gate, wsWs, wsWg);
  hist_kernel   <<<NCHUNK, 256, 0, stream>>>(edge_index, hist, lscan);
  scanc_kernel  <<<NBUCK,  256, 0, stream>>>(hist, total);   // in-place -> cscan
  scanb_kernel  <<<1,      256, 0, stream>>>(total, base);
  scatter_kernel<<<NCHUNK, 512, 0, stream>>>(edge_index, lscan, hist, base,
                                             frames, payload);
  reduce_kernel <<<NBUCK,  256, 0, stream>>>(payload, base, acc);

  node_kernel<<<768, 256, 0, stream>>>(
      scalar_rep, vector_rep, W_down, W_frames, b_scalar,
      W_up, b_gate, wsWs, wsWg, acc,
      out, out + (size_t)N_NODES * 128);
}

// Round 17
// 195.145 us; speedup vs baseline: 1.0921x; 1.0921x over previous
//
#include <hip/hip_runtime.h>
#include <hip/hip_bf16.h>
#include <math.h>

#define N_NODES 100000
#define N_EDGES 3200000
#define NB 16           // nodes per block-iteration (node phase)
#define EPSV 1e-8f

#define NBUCK 782                   // buckets of 128 nodes
#define NCHUNK 1280                 // edge chunks
#define CHUNK_E 2500                // edges per chunk

#define CE 256                      // reduce: entries per staging chunk
#define RS 264                      // reduce: staging row stride (u16)

typedef __attribute__((ext_vector_type(8))) short short8;
typedef __attribute__((ext_vector_type(4))) float f32x4;
typedef __attribute__((ext_vector_type(4), aligned(4))) unsigned int uint4u; // unaligned-capable

static __device__ __forceinline__ unsigned short f2bf(float x) {
  union { float f; unsigned int u; } c; c.f = x;
  unsigned int r = c.u + 0x7fff + ((c.u >> 16) & 1);   // RNE
  return (unsigned short)(r >> 16);
}
static __device__ __forceinline__ unsigned int f2bf_bits(unsigned int u) {
  unsigned int r = u + 0x7fff + ((u >> 16) & 1);       // RNE on raw bits
  return r >> 16;
}

// ------- A: per-chunk histogram + in-register bucket scan -> hist, lscan ----
__global__ __launch_bounds__(256) void hist_kernel(const int* __restrict__ row,
                                                   unsigned short* __restrict__ hist,
                                                   unsigned short* __restrict__ lscan) {
  __shared__ int lh[NBUCK];
  __shared__ int wtot[4];
  for (int i = threadIdx.x; i < NBUCK; i += 256) lh[i] = 0;
  __syncthreads();
  const int c = blockIdx.x;
  const int e1 = c * CHUNK_E + CHUNK_E;
  for (int e = c * CHUNK_E + threadIdx.x; e < e1; e += 256)
    atomicAdd(&lh[row[e] >> 7], 1);
  __syncthreads();
  // shuffle scan: thread t owns buckets 4t..4t+3
  const int t = threadIdx.x, lane = t & 63, wid = t >> 6;
  const int b0 = t * 4;
  int h[4];
#pragma unroll
  for (int j = 0; j < 4; ++j) h[j] = (b0 + j < NBUCK) ? lh[b0 + j] : 0;
  int s = h[0] + h[1] + h[2] + h[3];
  int incl = s;
#pragma unroll
  for (int d = 1; d < 64; d <<= 1) {
    int o = __shfl_up(incl, d);
    if (lane >= d) incl += o;
  }
  if (lane == 63) wtot[wid] = incl;
  __syncthreads();
  int pre = incl - s;
  for (int w = 0; w < wid; ++w) pre += wtot[w];
#pragma unroll
  for (int j = 0; j < 4; ++j) {
    if (b0 + j < NBUCK) {
      hist [(size_t)c * NBUCK + b0 + j] = (unsigned short)h[j];
      lscan[(size_t)c * NBUCK + b0 + j] = (unsigned short)pre;
    }
    pre += h[j];
  }
}

// ------- B1: exclusive scan over chunks per bucket -> cscan (hist kept) -----
__global__ __launch_bounds__(256) void scanc_kernel(const unsigned short* __restrict__ hist,
                                                    unsigned short* __restrict__ cscan,
                                                    int* __restrict__ total) {
  __shared__ int s[2][NCHUNK];
  const int b = blockIdx.x;
  const int t = threadIdx.x;
  for (int i = t; i < NCHUNK; i += 256) s[0][i] = hist[(size_t)i * NBUCK + b];
  __syncthreads();
  int src = 0;
  for (int off = 1; off < NCHUNK; off <<= 1) {
    int dst = src ^ 1;
    for (int i = t; i < NCHUNK; i += 256)
      s[dst][i] = s[src][i] + ((i >= off) ? s[src][i - off] : 0);
    __syncthreads();
    src = dst;
  }
  for (int i = t; i < NCHUNK; i += 256)
    cscan[(size_t)i * NBUCK + b] = (unsigned short)((i == 0) ? 0 : s[src][i - 1]);
  if (t == 0) total[b] = s[src][NCHUNK - 1];
}

// ---------------- B2: exclusive scan over buckets ---------------------------
__global__ __launch_bounds__(256) void scanb_kernel(const int* __restrict__ total,
                                                    int* __restrict__ base) {
  __shared__ int s[2][1024];
  const int t = threadIdx.x;
  for (int i = t; i < 1024; i += 256) s[0][i] = (i < NBUCK) ? total[i] : 0;
  __syncthreads();
  int src = 0;
  for (int off = 1; off < 1024; off <<= 1) {
    int dst = src ^ 1;
    for (int i = t; i < 1024; i += 256)
      s[dst][i] = s[src][i] + ((i >= off) ? s[src][i - off] : 0);
    __syncthreads();
    src = dst;
  }
  for (int i = t; i <= NBUCK; i += 256) base[i] = (i == 0) ? 0 : s[src][i - 1];
}

// ------- C: scatter — wide unaligned reads, LDS sort, flat burst write ------
__global__ __launch_bounds__(512) void scatter_kernel(const int* __restrict__ row,
                                                      const unsigned short* __restrict__ lscan,
                                                      const unsigned short* __restrict__ cscan,
                                                      const int* __restrict__ base,
                                                      const float* __restrict__ frames,
                                                      unsigned int* __restrict__ payload) {
  __shared__ unsigned int sbuf[CHUNK_E * 5];                // 50 KB
  __shared__ unsigned short bkt[CHUNK_E];                   // 5 KB
  __shared__ int lstart[NBUCK], loff[NBUCK], runG[NBUCK];   // 9.4 KB
  const int c = blockIdx.x, tid = threadIdx.x;

  for (int i = tid; i < NBUCK; i += 512) {
    int st = (int)lscan[(size_t)c * NBUCK + i];
    lstart[i] = st;
    loff[i] = st;
    runG[i] = base[i] + (int)cscan[(size_t)c * NBUCK + i];
  }
  __syncthreads();

  // phase A: 3 wide loads per edge (2x dwordx4 + 1 dword over 36B)
  const int e0 = c * CHUNK_E;
  for (int e = e0 + tid; e < e0 + CHUNK_E; e += 512) {
    int r = row[e];
    const unsigned int* fp = (const unsigned int*)frames + (size_t)e * 9;
    uint4u qa = *(const uint4u*)fp;
    uint4u qb = *(const uint4u*)(fp + 4);
    unsigned int q8 = fp[8];
    unsigned int w0 = f2bf_bits(qa.x) | (f2bf_bits(qa.y) << 16);
    unsigned int w1 = f2bf_bits(qa.z) | (f2bf_bits(qa.w) << 16);
    unsigned int w2 = f2bf_bits(qb.x) | (f2bf_bits(qb.y) << 16);
    unsigned int w3 = f2bf_bits(qb.z) | (f2bf_bits(qb.w) << 16);
    unsigned int w4 = f2bf_bits(q8)   | ((unsigned)(r & 127) << 16);
    int b = r >> 7;
    int p = atomicAdd(&loff[b], 1);
    bkt[p] = (unsigned short)b;
    unsigned int* d = sbuf + p * 5;
    d[0] = w0; d[1] = w1; d[2] = w2; d[3] = w3; d[4] = w4;
  }
  __syncthreads();

  // phase B: flat per-entry copy — full lanes, run-contiguous destinations
  for (int p = tid; p < CHUNK_E; p += 512) {
    int b = bkt[p];
    int g = runG[b] + (p - lstart[b]);
    const unsigned int* s = sbuf + p * 5;
    unsigned int* d = payload + (size_t)g * 5;
    d[0] = s[0]; d[1] = s[1]; d[2] = s[2]; d[3] = s[3]; d[4] = s[4];
  }
}

// ------- D: per-bucket (128-node) reduce — one-hot MFMA, zero atomics -------
__global__ __launch_bounds__(256) void reduce_kernel(const unsigned int* __restrict__ payload,
                                                     const int* __restrict__ base,
                                                     float* __restrict__ acc) {
  __shared__ unsigned short stg[2][16][RS];
  const int tid = threadIdx.x;
  const int b = blockIdx.x;
  const int wid = tid >> 6, lane = tid & 63;
  const int lr = lane & 15, lk = lane >> 4;

  for (int i = tid; i < RS; i += 256) {            // count row = 1.0 bf16
    stg[0][9][i] = 0x3F80; stg[1][9][i] = 0x3F80;
  }

  const int p0 = base[b], p1 = base[b + 1];
  const int nch = (p1 - p0 + CE - 1) / CE;
  const int s0 = wid * 2;
  const unsigned na = (unsigned)((s0 << 4) | lr);       // per-lane full-id consts
  const unsigned nbod = (unsigned)(((s0 + 1) << 4) | lr);

  f32x4 c0 = {0.f, 0.f, 0.f, 0.f};
  f32x4 c1 = {0.f, 0.f, 0.f, 0.f};

  auto STAGE = [&](int c, int buf) {
    int p = p0 + c * CE + tid;
    if (p < p1) {
      const unsigned int* s = payload + (size_t)p * 5;
      uint4u q = *(const uint4u*)s;                  // wide sequential load
      unsigned int w4 = s[4];
      stg[buf][0][tid] = (unsigned short)q.x;
      stg[buf][1][tid] = (unsigned short)(q.x >> 16);
      stg[buf][2][tid] = (unsigned short)q.y;
      stg[buf][3][tid] = (unsigned short)(q.y >> 16);
      stg[buf][4][tid] = (unsigned short)q.z;
      stg[buf][5][tid] = (unsigned short)(q.z >> 16);
      stg[buf][6][tid] = (unsigned short)q.w;
      stg[buf][7][tid] = (unsigned short)(q.w >> 16);
      stg[buf][8][tid] = (unsigned short)w4;
      stg[buf][10][tid] = (unsigned short)(w4 >> 16);
    } else {
#pragma unroll
      for (int k = 0; k < 9; ++k) stg[buf][k][tid] = 0;   // keep B finite
      stg[buf][10][tid] = 0xFFFF;                         // matches no id
    }
  };

  auto COMP = [&](int buf) {
#pragma unroll
    for (int g = 0; g < 8; ++g) {
      short8 bf = *(const short8*)&stg[buf][lr][g * 32 + lk * 8];
      short8 nv = *(const short8*)&stg[buf][10][g * 32 + lk * 8]; // broadcast
      short8 a0, a1;
#pragma unroll
      for (int j = 0; j < 8; ++j) {
        unsigned nid = (unsigned short)nv[j];
        a0[j] = (short)((nid == na)   ? 0x3F80 : 0);
        a1[j] = (short)((nid == nbod) ? 0x3F80 : 0);
      }
      c0 = __builtin_amdgcn_mfma_f32_16x16x32_bf16(a0, bf, c0, 0, 0, 0);
      c1 = __builtin_amdgcn_mfma_f32_16x16x32_bf16(a1, bf, c1, 0, 0, 0);
    }
  };

  if (nch > 0) {
    STAGE(0, 0);
    __syncthreads();
    for (int c = 0; c < nch; ++c) {
      if (c + 1 < nch) STAGE(c + 1, (c + 1) & 1);  // overlap with compute
      COMP(c & 1);
      __syncthreads();
    }
  }
  // writeout: D col = comp (lr), row = lk*4+j within subtile
  const int n0 = b << 7;
  if (lr < 10) {
#pragma unroll
    for (int j = 0; j < 4; ++j) {
      int r = lk * 4 + j;
      int x0 = n0 + s0 * 16 + r;
      int x1 = n0 + (s0 + 1) * 16 + r;
      if (x0 < N_NODES) acc[(size_t)x0 * 10 + lr] = c0[j];
      if (x1 < N_NODES) acc[(size_t)x1 * 10 + lr] = c1[j];
    }
  }
}

// ---------------- prep: pre-swizzle Ws/Wg into MFMA B-fragment layout -------
__global__ __launch_bounds__(256) void prep_kernel(const float* __restrict__ Ws,
                                                   const float* __restrict__ Wg,
                                                   unsigned short* __restrict__ wsWs,
                                                   unsigned short* __restrict__ wsWg) {
  int idx = blockIdx.x * 256 + threadIdx.x;     // 80 blocks -> 20480 threads
  if (idx < 8 * 5 * 512) {                      // ((nt*5+kk)*64 + l)*8 + j
    int j = idx & 7, l = (idx >> 3) & 63, t = idx >> 9;
    int nt = t / 5, kk = t - nt * 5;
    int o = nt * 16 + (l & 15);
    int m = kk * 32 + ((l >> 4) << 3) + j;
    wsWs[idx] = (m < 153) ? f2bf(Ws[o * 153 + m]) : (unsigned short)0;
  }
  if (idx < 4 * 512) {                          // ((kk*64 + l)*8 + j)
    int j = idx & 7, l = (idx >> 3) & 63, kk = idx >> 9;
    int v = l & 15;
    int m = kk * 32 + ((l >> 4) << 3) + j;
    wsWg[idx] = f2bf(Wg[v * 128 + m]);
  }
}

// ---------------- node phase: MFMA for big matvec + gate --------------------
__global__ __launch_bounds__(256, 4) void node_kernel(
    const float* __restrict__ scalar_rep,   // [N][128]
    const float* __restrict__ vrep,         // [N][16][3]
    const float* __restrict__ Wd,           // [16][16]
    const float* __restrict__ Wf,           // [3][16]
    const float* __restrict__ bs,           // [128]
    const float* __restrict__ Wu,           // [16][16]
    const float* __restrict__ bg,           // [16]
    const unsigned short* __restrict__ wsWs,// pre-swizzled B-frags [8][5][64][8]
    const unsigned short* __restrict__ wsWg,// pre-swizzled B-frags [4][64][8]
    const float* __restrict__ acc,          // [N][10]
    float* __restrict__ out_s,              // [N][128]
    float* __restrict__ out_v) {            // [N][16][3]
  __shared__ alignas(16) unsigned short s_mergedb[16 * 168];  // bf16, pad->168
  __shared__ alignas(16) unsigned short s_sfb[16 * 136];      // bf16 silu
  __shared__ float s_vrep[16][48];
  __shared__ float s_vh[16][48];
  __shared__ float s_vdf[16][12];
  __shared__ float s_gate[16][16];
  __shared__ float s_WdT[256], s_WuT[256], s_Wf[48], s_bs[128], s_bg[16];

  const int tid = threadIdx.x;
  {
    int a = tid >> 4, b = tid & 15;
    s_WdT[b * 16 + a] = Wd[tid];
    s_WuT[b * 16 + a] = Wu[tid];
  }
  if (tid < 48) s_Wf[tid] = Wf[tid];
  if (tid < 128) s_bs[tid] = bs[tid];
  if (tid < 16) s_bg[tid] = bg[tid];
  if (tid < 240) {                       // zero merged pad cols 153..167
    int r = tid / 15, c = 153 + tid % 15;
    s_mergedb[r * 168 + c] = 0;
  }

  const int i4 = tid >> 4, j4 = tid & 15;
  const int wid = tid >> 6, lane = tid & 63;
  const int lr = lane & 15, lk = lane >> 4;

  const float4* scalar4 = (const float4*)scalar_rep;
  const float4* vrep4 = (const float4*)vrep;

  for (int g = blockIdx.x; g < N_NODES / NB; g += gridDim.x) {
    const int n0 = g * NB;
    __syncthreads();   // previous iteration consumers done
    // stage scalar_rep -> bf16 merged[.,0:128]
    for (int idx = tid; idx < 512; idx += 256) {
      float4 v = scalar4[(size_t)n0 * 32 + idx];
      int r = idx >> 5, c4 = idx & 31;
      unsigned short* d = s_mergedb + r * 168 + c4 * 4;
      d[0] = f2bf(v.x); d[1] = f2bf(v.y); d[2] = f2bf(v.z); d[3] = f2bf(v.w);
    }
    // stage vector_rep f32
    for (int idx = tid; idx < 192; idx += 256)
      ((float4*)s_vrep)[idx] = vrep4[(size_t)n0 * 12 + idx];
    __syncthreads();
    // vh + vnorm
    {
      float a0 = 0.f, a1 = 0.f, a2 = 0.f;
#pragma unroll
      for (int v = 0; v < 16; ++v) {
        float w = s_WdT[v * 16 + j4];
        a0 += s_vrep[i4][v * 3 + 0] * w;
        a1 += s_vrep[i4][v * 3 + 1] * w;
        a2 += s_vrep[i4][v * 3 + 2] * w;
      }
      s_vh[i4][j4]      = a0;
      s_vh[i4][16 + j4] = a1;
      s_vh[i4][32 + j4] = a2;
      s_mergedb[i4 * 168 + 128 + j4] = f2bf(sqrtf(a0 * a0 + a1 * a1 + a2 * a2 + EPSV));
    }
    // vdf
    if (j4 < 9) {
      int t = j4 / 3, f = j4 - t * 3;
      float a = 0.f;
#pragma unroll
      for (int v = 0; v < 16; ++v)
        a += s_vrep[i4][v * 3 + t] * s_Wf[f * 16 + v];
      s_vdf[i4][j4] = a;
    }
    __syncthreads();
    // scalar_hidden -> merged[.,144:153]
    if (j4 < 9) {
      int f = j4 / 3, s = j4 - f * 3;
      const float* a = acc + (size_t)(n0 + i4) * 10;
      float c = fmaxf(a[9], 1.0f);
      float sum = a[s * 3 + 0] * s_vdf[i4][0 + f] +
                  a[s * 3 + 1] * s_vdf[i4][3 + f] +
                  a[s * 3 + 2] * s_vdf[i4][6 + f];
      s_mergedb[i4 * 168 + 144 + j4] = f2bf(sum / c);
    }
    __syncthreads();
    // big MFMA: merged[16x160] @ WsT[160x128]; wave wid owns N-tiles 2w,2w+1
    {
      const int nt0 = wid * 2;
      short8 afrag[5];
#pragma unroll
      for (int kk = 0; kk < 5; ++kk)
        afrag[kk] = *(const short8*)(s_mergedb + lr * 168 + kk * 32 + lk * 8);
      float b0v = s_bs[nt0 * 16 + lr], b1v = s_bs[nt0 * 16 + 16 + lr];
      f32x4 acc0 = {b0v, b0v, b0v, b0v};
      f32x4 acc1 = {b1v, b1v, b1v, b1v};
#pragma unroll
      for (int kk = 0; kk < 5; ++kk) {
        short8 bf0 = *(const short8*)(wsWs + (((nt0 * 5 + kk) << 6) + lane) * 8);
        short8 bf1 = *(const short8*)(wsWs + ((((nt0 + 1) * 5 + kk) << 6) + lane) * 8);
        acc0 = __builtin_amdgcn_mfma_f32_16x16x32_bf16(afrag[kk], bf0, acc0, 0, 0, 0);
        acc1 = __builtin_amdgcn_mfma_f32_16x16x32_bf16(afrag[kk], bf1, acc1, 0, 0, 0);
      }
#pragma unroll
      for (int j = 0; j < 4; ++j) {
        int node = lk * 4 + j;
        float x0 = acc0[j];
        float sf0 = x0 / (1.0f + __expf(-x0));
        out_s[(size_t)(n0 + node) * 128 + nt0 * 16 + lr] = sf0;
        s_sfb[node * 136 + nt0 * 16 + lr] = f2bf(sf0);
        float x1 = acc1[j];
        float sf1 = x1 / (1.0f + __expf(-x1));
        out_s[(size_t)(n0 + node) * 128 + nt0 * 16 + 16 + lr] = sf1;
        s_sfb[node * 136 + nt0 * 16 + 16 + lr] = f2bf(sf1);
      }
    }
    __syncthreads();
    // gate MFMA on wave 0: sf[16x128] @ WgT[128x16]
    if (wid == 0) {
      float gb = s_bg[lr];
      f32x4 gacc = {gb, gb, gb, gb};
#pragma unroll
      for (int kk = 0; kk < 4; ++kk) {
        short8 ga = *(const short8*)(s_sfb + lr * 136 + kk * 32 + lk * 8);
        short8 gw = *(const short8*)(wsWg + (((kk << 6) + lane) * 8));
        gacc = __builtin_amdgcn_mfma_f32_16x16x32_bf16(ga, gw, gacc, 0, 0, 0);
      }
#pragma unroll
      for (int j = 0; j < 4; ++j) {
        int node = lk * 4 + j;
        s_gate[node][lr] = 1.0f / (1.0f + __expf(-gacc[j]));
      }
    }
    __syncthreads();
    // v_up + gated output
    {
      float b0 = 0.f, b1 = 0.f, b2 = 0.f;
#pragma unroll
      for (int h = 0; h < 16; ++h) {
        float w = s_WuT[h * 16 + j4];
        b0 += s_vh[i4][h]      * w;
        b1 += s_vh[i4][16 + h] * w;
        b2 += s_vh[i4][32 + h] * w;
      }
      float gt = s_gate[i4][j4];
      size_t basep = (size_t)(n0 + i4) * 48 + (size_t)j4 * 3;
      out_v[basep + 0] = b0 * gt;
      out_v[basep + 1] = b1 * gt;
      out_v[basep + 2] = b2 * gt;
    }
  }
}

extern "C" void kernel_launch(void* const* d_in, const int* in_sizes, int n_in,
                              void* d_out, int out_size, void* d_ws, size_t ws_size,
                              hipStream_t stream) {
  const float* scalar_rep = (const float*)d_in[0];
  const float* vector_rep = (const float*)d_in[1];
  const float* frames     = (const float*)d_in[2];
  const float* W_down     = (const float*)d_in[3];
  const float* W_frames   = (const float*)d_in[4];
  const float* W_scalar   = (const float*)d_in[5];
  const float* b_scalar   = (const float*)d_in[6];
  const float* W_up       = (const float*)d_in[7];
  const float* W_gate     = (const float*)d_in[8];
  const float* b_gate     = (const float*)d_in[9];
  const int*   edge_index = (const int*)d_in[10];   // [2][E], row = first E

  float* out = (float*)d_out;

  // workspace layout
  unsigned short* hist  = (unsigned short*)d_ws;            // 1280*782 u16
  unsigned short* lscan = hist  + (size_t)NCHUNK * NBUCK;   // 1280*782 u16
  unsigned short* cscan = lscan + (size_t)NCHUNK * NBUCK;   // 1280*782 u16
  int*   total   = (int*)(cscan + (size_t)NCHUNK * NBUCK);  // 800
  int*   base    = total + 800;                             // 800
  unsigned int* payload = (unsigned int*)(base + 800);      // 3.2M * 5 dw = 64MB
  float* acc     = (float*)(payload + 16000000);            // 1M floats
  unsigned short* wsWs = (unsigned short*)(acc + 1000000);  // 20480 bf16
  unsigned short* wsWg = wsWs + 20480;                      // 2048 bf16

  prep_kernel   <<<80,     256, 0, stream>>>(W_scalar, W_gate, wsWs, wsWg);
  hist_kernel   <<<NCHUNK, 256, 0, stream>>>(edge_index, hist, lscan);
  scanc_kernel  <<<NBUCK,  256, 0, stream>>>(hist, cscan, total);
  scanb_kernel  <<<1,      256, 0, stream>>>(total, base);
  scatter_kernel<<<NCHUNK, 512, 0, stream>>>(edge_index, lscan, cscan, base,
                                             frames, payload);
  reduce_kernel <<<NBUCK,  256, 0, stream>>>(payload, base, acc);

  node_kernel<<<768, 256, 0, stream>>>(
      scalar_rep, vector_rep, W_down, W_frames, b_scalar,
      W_up, b_gate, wsWs, wsWg, acc,
      out, out + (size_t)N_NODES * 128);
}

// Round 18
// 190.946 us; speedup vs baseline: 1.1162x; 1.0220x over previous
//
#include <hip/hip_runtime.h>
#include <hip/hip_bf16.h>
#include <math.h>

#define N_NODES 100000
#define N_EDGES 3200000
#define NB 16           // nodes per block-iteration (node phase)
#define EPSV 1e-8f

#define NBUCK 782                   // buckets of 128 nodes
#define NCHUNK 1280                 // edge chunks
#define CHUNK_E 2500                // edges per chunk

#define CE 256                      // reduce: entries per staging chunk
#define RS 264                      // reduce: staging row stride (u16)

typedef __attribute__((ext_vector_type(8))) short short8;
typedef __attribute__((ext_vector_type(4))) float f32x4;
typedef __attribute__((ext_vector_type(4), aligned(4))) unsigned int uint4u; // unaligned-capable

static __device__ __forceinline__ unsigned short f2bf(float x) {
  union { float f; unsigned int u; } c; c.f = x;
  unsigned int r = c.u + 0x7fff + ((c.u >> 16) & 1);   // RNE
  return (unsigned short)(r >> 16);
}
static __device__ __forceinline__ unsigned int f2bf_bits(unsigned int u) {
  unsigned int r = u + 0x7fff + ((u >> 16) & 1);       // RNE on raw bits
  return r >> 16;
}

// ------- A: per-chunk histogram + in-register bucket scan -> hist, lscan ----
__global__ __launch_bounds__(256) void hist_kernel(const int* __restrict__ row,
                                                   unsigned short* __restrict__ hist,
                                                   unsigned short* __restrict__ lscan) {
  __shared__ int lh[NBUCK];
  __shared__ int wtot[4];
  for (int i = threadIdx.x; i < NBUCK; i += 256) lh[i] = 0;
  __syncthreads();
  const int c = blockIdx.x;
  const int e1 = c * CHUNK_E + CHUNK_E;
  for (int e = c * CHUNK_E + threadIdx.x; e < e1; e += 256)
    atomicAdd(&lh[row[e] >> 7], 1);
  __syncthreads();
  // shuffle scan: thread t owns buckets 4t..4t+3
  const int t = threadIdx.x, lane = t & 63, wid = t >> 6;
  const int b0 = t * 4;
  int h[4];
#pragma unroll
  for (int j = 0; j < 4; ++j) h[j] = (b0 + j < NBUCK) ? lh[b0 + j] : 0;
  int s = h[0] + h[1] + h[2] + h[3];
  int incl = s;
#pragma unroll
  for (int d = 1; d < 64; d <<= 1) {
    int o = __shfl_up(incl, d);
    if (lane >= d) incl += o;
  }
  if (lane == 63) wtot[wid] = incl;
  __syncthreads();
  int pre = incl - s;
  for (int w = 0; w < wid; ++w) pre += wtot[w];
#pragma unroll
  for (int j = 0; j < 4; ++j) {
    if (b0 + j < NBUCK) {
      hist [(size_t)c * NBUCK + b0 + j] = (unsigned short)h[j];
      lscan[(size_t)c * NBUCK + b0 + j] = (unsigned short)pre;
    }
    pre += h[j];
  }
}

// ------- B1: exclusive scan over chunks per bucket -> cscan (hist kept) -----
__global__ __launch_bounds__(256) void scanc_kernel(const unsigned short* __restrict__ hist,
                                                    unsigned short* __restrict__ cscan,
                                                    int* __restrict__ total) {
  __shared__ int s[2][NCHUNK];
  const int b = blockIdx.x;
  const int t = threadIdx.x;
  for (int i = t; i < NCHUNK; i += 256) s[0][i] = hist[(size_t)i * NBUCK + b];
  __syncthreads();
  int src = 0;
  for (int off = 1; off < NCHUNK; off <<= 1) {
    int dst = src ^ 1;
    for (int i = t; i < NCHUNK; i += 256)
      s[dst][i] = s[src][i] + ((i >= off) ? s[src][i - off] : 0);
    __syncthreads();
    src = dst;
  }
  for (int i = t; i < NCHUNK; i += 256)
    cscan[(size_t)i * NBUCK + b] = (unsigned short)((i == 0) ? 0 : s[src][i - 1]);
  if (t == 0) total[b] = s[src][NCHUNK - 1];
}

// ---------------- B2: exclusive scan over buckets ---------------------------
__global__ __launch_bounds__(256) void scanb_kernel(const int* __restrict__ total,
                                                    int* __restrict__ base) {
  __shared__ int s[2][1024];
  const int t = threadIdx.x;
  for (int i = t; i < 1024; i += 256) s[0][i] = (i < NBUCK) ? total[i] : 0;
  __syncthreads();
  int src = 0;
  for (int off = 1; off < 1024; off <<= 1) {
    int dst = src ^ 1;
    for (int i = t; i < 1024; i += 256)
      s[dst][i] = s[src][i] + ((i >= off) ? s[src][i - off] : 0);
    __syncthreads();
    src = dst;
  }
  for (int i = t; i <= NBUCK; i += 256) base[i] = (i == 0) ? 0 : s[src][i - 1];
}

// ------- C: scatter — wide unaligned reads, LDS sort, flat burst write ------
__global__ __launch_bounds__(512) void scatter_kernel(const int* __restrict__ row,
                                                      const unsigned short* __restrict__ lscan,
                                                      const unsigned short* __restrict__ cscan,
                                                      const int* __restrict__ base,
                                                      const float* __restrict__ frames,
                                                      unsigned int* __restrict__ payload) {
  __shared__ unsigned int sbuf[CHUNK_E * 5];                // 50 KB
  __shared__ unsigned short bkt[CHUNK_E];                   // 5 KB
  __shared__ int lstart[NBUCK], loff[NBUCK], runG[NBUCK];   // 9.4 KB
  const int c = blockIdx.x, tid = threadIdx.x;

  for (int i = tid; i < NBUCK; i += 512) {
    int st = (int)lscan[(size_t)c * NBUCK + i];
    lstart[i] = st;
    loff[i] = st;
    runG[i] = base[i] + (int)cscan[(size_t)c * NBUCK + i];
  }
  __syncthreads();

  // phase A: 3 wide loads per edge (2x dwordx4 + 1 dword over 36B)
  const int e0 = c * CHUNK_E;
  for (int e = e0 + tid; e < e0 + CHUNK_E; e += 512) {
    int r = row[e];
    const unsigned int* fp = (const unsigned int*)frames + (size_t)e * 9;
    uint4u qa = *(const uint4u*)fp;
    uint4u qb = *(const uint4u*)(fp + 4);
    unsigned int q8 = fp[8];
    unsigned int w0 = f2bf_bits(qa.x) | (f2bf_bits(qa.y) << 16);
    unsigned int w1 = f2bf_bits(qa.z) | (f2bf_bits(qa.w) << 16);
    unsigned int w2 = f2bf_bits(qb.x) | (f2bf_bits(qb.y) << 16);
    unsigned int w3 = f2bf_bits(qb.z) | (f2bf_bits(qb.w) << 16);
    unsigned int w4 = f2bf_bits(q8)   | ((unsigned)(r & 127) << 16);
    int b = r >> 7;
    int p = atomicAdd(&loff[b], 1);
    bkt[p] = (unsigned short)b;
    unsigned int* d = sbuf + p * 5;
    d[0] = w0; d[1] = w1; d[2] = w2; d[3] = w3; d[4] = w4;
  }
  __syncthreads();

  // phase B: flat per-entry copy — full lanes, run-contiguous destinations
  for (int p = tid; p < CHUNK_E; p += 512) {
    int b = bkt[p];
    int g = runG[b] + (p - lstart[b]);
    const unsigned int* s = sbuf + p * 5;
    unsigned int* d = payload + (size_t)g * 5;
    d[0] = s[0]; d[1] = s[1]; d[2] = s[2]; d[3] = s[3]; d[4] = s[4];
  }
}

// ------- D: per-bucket (128-node) reduce — one-hot MFMA, zero atomics -------
__global__ __launch_bounds__(256) void reduce_kernel(const unsigned int* __restrict__ payload,
                                                     const int* __restrict__ base,
                                                     float* __restrict__ acc) {
  __shared__ unsigned short stg[2][16][RS];
  const int tid = threadIdx.x;
  const int b = blockIdx.x;
  const int wid = tid >> 6, lane = tid & 63;
  const int lr = lane & 15, lk = lane >> 4;

  for (int i = tid; i < RS; i += 256) {            // count row = 1.0 bf16
    stg[0][9][i] = 0x3F80; stg[1][9][i] = 0x3F80;
  }

  const int p0 = base[b], p1 = base[b + 1];
  const int nch = (p1 - p0 + CE - 1) / CE;
  const int s0 = wid * 2;
  const unsigned na = (unsigned)((s0 << 4) | lr);       // per-lane full-id consts
  const unsigned nbod = (unsigned)(((s0 + 1) << 4) | lr);

  f32x4 c0 = {0.f, 0.f, 0.f, 0.f};
  f32x4 c1 = {0.f, 0.f, 0.f, 0.f};

  auto STAGE = [&](int c, int buf) {
    int p = p0 + c * CE + tid;
    if (p < p1) {
      const unsigned int* s = payload + (size_t)p * 5;
      uint4u q = *(const uint4u*)s;                  // wide sequential load
      unsigned int w4 = s[4];
      stg[buf][0][tid] = (unsigned short)q.x;
      stg[buf][1][tid] = (unsigned short)(q.x >> 16);
      stg[buf][2][tid] = (unsigned short)q.y;
      stg[buf][3][tid] = (unsigned short)(q.y >> 16);
      stg[buf][4][tid] = (unsigned short)q.z;
      stg[buf][5][tid] = (unsigned short)(q.z >> 16);
      stg[buf][6][tid] = (unsigned short)q.w;
      stg[buf][7][tid] = (unsigned short)(q.w >> 16);
      stg[buf][8][tid] = (unsigned short)w4;
      stg[buf][10][tid] = (unsigned short)(w4 >> 16);
    } else {
#pragma unroll
      for (int k = 0; k < 9; ++k) stg[buf][k][tid] = 0;   // keep B finite
      stg[buf][10][tid] = 0xFFFF;                         // matches no id
    }
  };

  auto COMP = [&](int buf) {
#pragma unroll
    for (int g = 0; g < 8; ++g) {
      short8 bf = *(const short8*)&stg[buf][lr][g * 32 + lk * 8];
      short8 nv = *(const short8*)&stg[buf][10][g * 32 + lk * 8]; // broadcast
      short8 a0, a1;
#pragma unroll
      for (int j = 0; j < 8; ++j) {
        unsigned nid = (unsigned short)nv[j];
        a0[j] = (short)((nid == na)   ? 0x3F80 : 0);
        a1[j] = (short)((nid == nbod) ? 0x3F80 : 0);
      }
      c0 = __builtin_amdgcn_mfma_f32_16x16x32_bf16(a0, bf, c0, 0, 0, 0);
      c1 = __builtin_amdgcn_mfma_f32_16x16x32_bf16(a1, bf, c1, 0, 0, 0);
    }
  };

  if (nch > 0) {
    STAGE(0, 0);
    __syncthreads();
    for (int c = 0; c < nch; ++c) {
      if (c + 1 < nch) STAGE(c + 1, (c + 1) & 1);  // overlap with compute
      COMP(c & 1);
      __syncthreads();
    }
  }
  // writeout: D col = comp (lr), row = lk*4+j within subtile
  const int n0 = b << 7;
  if (lr < 10) {
#pragma unroll
    for (int j = 0; j < 4; ++j) {
      int r = lk * 4 + j;
      int x0 = n0 + s0 * 16 + r;
      int x1 = n0 + (s0 + 1) * 16 + r;
      if (x0 < N_NODES) acc[(size_t)x0 * 10 + lr] = c0[j];
      if (x1 < N_NODES) acc[(size_t)x1 * 10 + lr] = c1[j];
    }
  }
}

// ---------------- prep: pre-swizzle Ws/Wg into MFMA B-fragment layout -------
__global__ __launch_bounds__(256) void prep_kernel(const float* __restrict__ Ws,
                                                   const float* __restrict__ Wg,
                                                   unsigned short* __restrict__ wsWs,
                                                   unsigned short* __restrict__ wsWg) {
  int idx = blockIdx.x * 256 + threadIdx.x;     // 80 blocks -> 20480 threads
  if (idx < 8 * 5 * 512) {                      // ((nt*5+kk)*64 + l)*8 + j
    int j = idx & 7, l = (idx >> 3) & 63, t = idx >> 9;
    int nt = t / 5, kk = t - nt * 5;
    int o = nt * 16 + (l & 15);
    int m = kk * 32 + ((l >> 4) << 3) + j;
    wsWs[idx] = (m < 153) ? f2bf(Ws[o * 153 + m]) : (unsigned short)0;
  }
  if (idx < 4 * 512) {                          // ((kk*64 + l)*8 + j)
    int j = idx & 7, l = (idx >> 3) & 63, kk = idx >> 9;
    int v = l & 15;
    int m = kk * 32 + ((l >> 4) << 3) + j;
    wsWg[idx] = f2bf(Wg[v * 128 + m]);
  }
}

// ------- node phase: MFMA, 4 barriers/group, wave-redundant gate ------------
__global__ __launch_bounds__(256, 4) void node_kernel(
    const float* __restrict__ scalar_rep,   // [N][128]
    const float* __restrict__ vrep,         // [N][16][3]
    const float* __restrict__ Wd,           // [16][16]
    const float* __restrict__ Wf,           // [3][16]
    const float* __restrict__ bs,           // [128]
    const float* __restrict__ Wu,           // [16][16]
    const float* __restrict__ bg,           // [16]
    const unsigned short* __restrict__ wsWs,// pre-swizzled B-frags [8][5][64][8]
    const unsigned short* __restrict__ wsWg,// pre-swizzled B-frags [4][64][8]
    const float* __restrict__ acc,          // [N][10]
    float* __restrict__ out_s,              // [N][128]
    float* __restrict__ out_v) {            // [N][16][3]
  __shared__ alignas(16) unsigned short s_mergedb[16 * 168];  // bf16, pad->168
  __shared__ alignas(16) unsigned short s_sfb[16 * 136];      // bf16 silu
  __shared__ float s_vrep[16][48];
  __shared__ float s_vh[16][48];
  __shared__ float s_WdT[256], s_WuT[256], s_Wf[48], s_bs[128], s_bg[16];

  const int tid = threadIdx.x;
  {
    int a = tid >> 4, b = tid & 15;
    s_WdT[b * 16 + a] = Wd[tid];
    s_WuT[b * 16 + a] = Wu[tid];
  }
  if (tid < 48) s_Wf[tid] = Wf[tid];
  if (tid < 128) s_bs[tid] = bs[tid];
  if (tid < 16) s_bg[tid] = bg[tid];
  if (tid < 240) {                       // zero merged pad cols 153..167
    int r = tid / 15, c = 153 + tid % 15;
    s_mergedb[r * 168 + c] = 0;
  }

  const int i4 = tid >> 4, j4 = tid & 15;
  const int wid = tid >> 6, lane = tid & 63;
  const int lr = lane & 15, lk = lane >> 4;

  const float4* scalar4 = (const float4*)scalar_rep;
  const float4* vrep4 = (const float4*)vrep;

  for (int g = blockIdx.x; g < N_NODES / NB; g += gridDim.x) {
    const int n0 = g * NB;
    __syncthreads();   // (A) previous iteration consumers done
    // stage scalar_rep -> bf16 merged[.,0:128]
    for (int idx = tid; idx < 512; idx += 256) {
      float4 v = scalar4[(size_t)n0 * 32 + idx];
      int r = idx >> 5, c4 = idx & 31;
      unsigned short* d = s_mergedb + r * 168 + c4 * 4;
      d[0] = f2bf(v.x); d[1] = f2bf(v.y); d[2] = f2bf(v.z); d[3] = f2bf(v.w);
    }
    // stage vector_rep f32
    for (int idx = tid; idx < 192; idx += 256)
      ((float4*)s_vrep)[idx] = vrep4[(size_t)n0 * 12 + idx];
    __syncthreads();   // (B)
    // vh + vnorm
    {
      float a0 = 0.f, a1 = 0.f, a2 = 0.f;
#pragma unroll
      for (int v = 0; v < 16; ++v) {
        float w = s_WdT[v * 16 + j4];
        a0 += s_vrep[i4][v * 3 + 0] * w;
        a1 += s_vrep[i4][v * 3 + 1] * w;
        a2 += s_vrep[i4][v * 3 + 2] * w;
      }
      s_vh[i4][j4]      = a0;
      s_vh[i4][16 + j4] = a1;
      s_vh[i4][32 + j4] = a2;
      s_mergedb[i4 * 168 + 128 + j4] = f2bf(sqrtf(a0 * a0 + a1 * a1 + a2 * a2 + EPSV));
    }
    // fused vdf + scalar_hidden (registers only, no cross-thread handoff)
    if (j4 < 9) {
      int f = j4 / 3, s = j4 - f * 3;
      float vt0 = 0.f, vt1 = 0.f, vt2 = 0.f;
#pragma unroll
      for (int v = 0; v < 16; ++v) {
        float w = s_Wf[f * 16 + v];
        vt0 += s_vrep[i4][v * 3 + 0] * w;
        vt1 += s_vrep[i4][v * 3 + 1] * w;
        vt2 += s_vrep[i4][v * 3 + 2] * w;
      }
      const float* a = acc + (size_t)(n0 + i4) * 10;
      float cnum = fmaxf(a[9], 1.0f);
      float sum = a[s * 3 + 0] * vt0 + a[s * 3 + 1] * vt1 + a[s * 3 + 2] * vt2;
      s_mergedb[i4 * 168 + 144 + j4] = f2bf(sum / cnum);
    }
    __syncthreads();   // (C)
    // big MFMA: merged[16x160] @ WsT[160x128]; wave wid owns N-tiles 2w,2w+1
    {
      const int nt0 = wid * 2;
      short8 afrag[5];
#pragma unroll
      for (int kk = 0; kk < 5; ++kk)
        afrag[kk] = *(const short8*)(s_mergedb + lr * 168 + kk * 32 + lk * 8);
      float b0v = s_bs[nt0 * 16 + lr], b1v = s_bs[nt0 * 16 + 16 + lr];
      f32x4 acc0 = {b0v, b0v, b0v, b0v};
      f32x4 acc1 = {b1v, b1v, b1v, b1v};
#pragma unroll
      for (int kk = 0; kk < 5; ++kk) {
        short8 bf0 = *(const short8*)(wsWs + (((nt0 * 5 + kk) << 6) + lane) * 8);
        short8 bf1 = *(const short8*)(wsWs + ((((nt0 + 1) * 5 + kk) << 6) + lane) * 8);
        acc0 = __builtin_amdgcn_mfma_f32_16x16x32_bf16(afrag[kk], bf0, acc0, 0, 0, 0);
        acc1 = __builtin_amdgcn_mfma_f32_16x16x32_bf16(afrag[kk], bf1, acc1, 0, 0, 0);
      }
#pragma unroll
      for (int j = 0; j < 4; ++j) {
        int node = lk * 4 + j;
        float x0 = acc0[j];
        float sf0 = x0 / (1.0f + __expf(-x0));
        out_s[(size_t)(n0 + node) * 128 + nt0 * 16 + lr] = sf0;
        s_sfb[node * 136 + nt0 * 16 + lr] = f2bf(sf0);
        float x1 = acc1[j];
        float sf1 = x1 / (1.0f + __expf(-x1));
        out_s[(size_t)(n0 + node) * 128 + nt0 * 16 + 16 + lr] = sf1;
        s_sfb[node * 136 + nt0 * 16 + 16 + lr] = f2bf(sf1);
      }
    }
    __syncthreads();   // (D)
    // gate MFMA redundantly on ALL waves + shfl distribute + v_up (no barrier)
    {
      float gb = s_bg[lr];
      f32x4 gacc = {gb, gb, gb, gb};
#pragma unroll
      for (int kk = 0; kk < 4; ++kk) {
        short8 ga = *(const short8*)(s_sfb + lr * 136 + kk * 32 + lk * 8);
        short8 gw = *(const short8*)(wsWg + (((kk << 6) + lane) * 8));
        gacc = __builtin_amdgcn_mfma_f32_16x16x32_bf16(ga, gw, gacc, 0, 0, 0);
      }
      // lane l needs gate[row = wid*4 + (l>>4)][col = l&15]
      // source lane = wid*16 + (l&15), element j = l>>4
      int src = (wid << 4) | (lane & 15);
      float g0 = __shfl(gacc[0], src);
      float g1 = __shfl(gacc[1], src);
      float g2 = __shfl(gacc[2], src);
      float g3 = __shfl(gacc[3], src);
      int q = lane >> 4;
      float gv = (q == 0) ? g0 : (q == 1) ? g1 : (q == 2) ? g2 : g3;
      float gt = 1.0f / (1.0f + __expf(-gv));
      // v_up + gated output (thread (i4, j4); gate row i4 = wid*4+(lane>>4))
      float b0 = 0.f, b1 = 0.f, b2 = 0.f;
#pragma unroll
      for (int h = 0; h < 16; ++h) {
        float w = s_WuT[h * 16 + j4];
        b0 += s_vh[i4][h]      * w;
        b1 += s_vh[i4][16 + h] * w;
        b2 += s_vh[i4][32 + h] * w;
      }
      size_t basep = (size_t)(n0 + i4) * 48 + (size_t)j4 * 3;
      out_v[basep + 0] = b0 * gt;
      out_v[basep + 1] = b1 * gt;
      out_v[basep + 2] = b2 * gt;
    }
  }
}

extern "C" void kernel_launch(void* const* d_in, const int* in_sizes, int n_in,
                              void* d_out, int out_size, void* d_ws, size_t ws_size,
                              hipStream_t stream) {
  const float* scalar_rep = (const float*)d_in[0];
  const float* vector_rep = (const float*)d_in[1];
  const float* frames     = (const float*)d_in[2];
  const float* W_down     = (const float*)d_in[3];
  const float* W_frames   = (const float*)d_in[4];
  const float* W_scalar   = (const float*)d_in[5];
  const float* b_scalar   = (const float*)d_in[6];
  const float* W_up       = (const float*)d_in[7];
  const float* W_gate     = (const float*)d_in[8];
  const float* b_gate     = (const float*)d_in[9];
  const int*   edge_index = (const int*)d_in[10];   // [2][E], row = first E

  float* out = (float*)d_out;

  // workspace layout
  unsigned short* hist  = (unsigned short*)d_ws;            // 1280*782 u16
  unsigned short* lscan = hist  + (size_t)NCHUNK * NBUCK;   // 1280*782 u16
  unsigned short* cscan = lscan + (size_t)NCHUNK * NBUCK;   // 1280*782 u16
  int*   total   = (int*)(cscan + (size_t)NCHUNK * NBUCK);  // 800
  int*   base    = total + 800;                             // 800
  unsigned int* payload = (unsigned int*)(base + 800);      // 3.2M * 5 dw = 64MB
  float* acc     = (float*)(payload + 16000000);            // 1M floats
  unsigned short* wsWs = (unsigned short*)(acc + 1000000);  // 20480 bf16
  unsigned short* wsWg = wsWs + 20480;                      // 2048 bf16

  prep_kernel   <<<80,     256, 0, stream>>>(W_scalar, W_gate, wsWs, wsWg);
  hist_kernel   <<<NCHUNK, 256, 0, stream>>>(edge_index, hist, lscan);
  scanc_kernel  <<<NBUCK,  256, 0, stream>>>(hist, cscan, total);
  scanb_kernel  <<<1,      256, 0, stream>>>(total, base);
  scatter_kernel<<<NCHUNK, 512, 0, stream>>>(edge_index, lscan, cscan, base,
                                             frames, payload);
  reduce_kernel <<<NBUCK,  256, 0, stream>>>(payload, base, acc);

  node_kernel<<<1024, 256, 0, stream>>>(
      scalar_rep, vector_rep, W_down, W_frames, b_scalar,
      W_up, b_gate, wsWs, wsWg, acc,
      out, out + (size_t)N_NODES * 128);
}

// Round 19
// 190.848 us; speedup vs baseline: 1.1167x; 1.0005x over previous
//
#include <hip/hip_runtime.h>
#include <hip/hip_bf16.h>
#include <math.h>

#define N_NODES 100000
#define N_EDGES 3200000
#define NB 16           // nodes per block-iteration (node phase)
#define EPSV 1e-8f

#define NBUCK 782                   // buckets of 128 nodes
#define NCHUNK 1280                 // edge chunks
#define CHUNK_E 2500                // edges per chunk

#define CE 256                      // reduce: entries per staging chunk
#define RS 264                      // reduce: staging row stride (u16)

typedef __attribute__((ext_vector_type(8))) short short8;
typedef __attribute__((ext_vector_type(4))) float f32x4;
typedef __attribute__((ext_vector_type(4), aligned(4))) unsigned int uint4u; // unaligned-capable

static __device__ __forceinline__ unsigned short f2bf(float x) {
  union { float f; unsigned int u; } c; c.f = x;
  unsigned int r = c.u + 0x7fff + ((c.u >> 16) & 1);   // RNE
  return (unsigned short)(r >> 16);
}
static __device__ __forceinline__ unsigned int f2bf_bits(unsigned int u) {
  unsigned int r = u + 0x7fff + ((u >> 16) & 1);       // RNE on raw bits
  return r >> 16;
}

// ------- A: per-chunk histogram + in-register bucket scan -> hist, lscan ----
__global__ __launch_bounds__(256) void hist_kernel(const int* __restrict__ row,
                                                   unsigned short* __restrict__ hist,
                                                   unsigned short* __restrict__ lscan) {
  __shared__ int lh[NBUCK];
  __shared__ int wtot[4];
  for (int i = threadIdx.x; i < NBUCK; i += 256) lh[i] = 0;
  __syncthreads();
  const int c = blockIdx.x;
  const int e1 = c * CHUNK_E + CHUNK_E;
  for (int e = c * CHUNK_E + threadIdx.x; e < e1; e += 256)
    atomicAdd(&lh[row[e] >> 7], 1);
  __syncthreads();
  // shuffle scan: thread t owns buckets 4t..4t+3
  const int t = threadIdx.x, lane = t & 63, wid = t >> 6;
  const int b0 = t * 4;
  int h[4];
#pragma unroll
  for (int j = 0; j < 4; ++j) h[j] = (b0 + j < NBUCK) ? lh[b0 + j] : 0;
  int s = h[0] + h[1] + h[2] + h[3];
  int incl = s;
#pragma unroll
  for (int d = 1; d < 64; d <<= 1) {
    int o = __shfl_up(incl, d);
    if (lane >= d) incl += o;
  }
  if (lane == 63) wtot[wid] = incl;
  __syncthreads();
  int pre = incl - s;
  for (int w = 0; w < wid; ++w) pre += wtot[w];
#pragma unroll
  for (int j = 0; j < 4; ++j) {
    if (b0 + j < NBUCK) {
      hist [(size_t)c * NBUCK + b0 + j] = (unsigned short)h[j];
      lscan[(size_t)c * NBUCK + b0 + j] = (unsigned short)pre;
    }
    pre += h[j];
  }
}

// ------- B1: exclusive scan over chunks per bucket -> cscan (hist kept) -----
__global__ __launch_bounds__(256) void scanc_kernel(const unsigned short* __restrict__ hist,
                                                    unsigned short* __restrict__ cscan,
                                                    int* __restrict__ total) {
  __shared__ int s[2][NCHUNK];
  const int b = blockIdx.x;
  const int t = threadIdx.x;
  for (int i = t; i < NCHUNK; i += 256) s[0][i] = hist[(size_t)i * NBUCK + b];
  __syncthreads();
  int src = 0;
  for (int off = 1; off < NCHUNK; off <<= 1) {
    int dst = src ^ 1;
    for (int i = t; i < NCHUNK; i += 256)
      s[dst][i] = s[src][i] + ((i >= off) ? s[src][i - off] : 0);
    __syncthreads();
    src = dst;
  }
  for (int i = t; i < NCHUNK; i += 256)
    cscan[(size_t)i * NBUCK + b] = (unsigned short)((i == 0) ? 0 : s[src][i - 1]);
  if (t == 0) total[b] = s[src][NCHUNK - 1];
}

// ---------------- B2: exclusive scan over buckets ---------------------------
__global__ __launch_bounds__(256) void scanb_kernel(const int* __restrict__ total,
                                                    int* __restrict__ base) {
  __shared__ int s[2][1024];
  const int t = threadIdx.x;
  for (int i = t; i < 1024; i += 256) s[0][i] = (i < NBUCK) ? total[i] : 0;
  __syncthreads();
  int src = 0;
  for (int off = 1; off < 1024; off <<= 1) {
    int dst = src ^ 1;
    for (int i = t; i < 1024; i += 256)
      s[dst][i] = s[src][i] + ((i >= off) ? s[src][i - off] : 0);
    __syncthreads();
    src = dst;
  }
  for (int i = t; i <= NBUCK; i += 256) base[i] = (i == 0) ? 0 : s[src][i - 1];
}

// ------- C: scatter — wide unaligned reads, LDS sort, flat dword burst ------
__global__ __launch_bounds__(512) void scatter_kernel(const int* __restrict__ row,
                                                      const unsigned short* __restrict__ lscan,
                                                      const unsigned short* __restrict__ cscan,
                                                      const int* __restrict__ base,
                                                      const float* __restrict__ frames,
                                                      unsigned int* __restrict__ payload) {
  __shared__ unsigned int sbuf[CHUNK_E * 5];                // 50 KB
  __shared__ unsigned short bkt[CHUNK_E];                   // 5 KB
  __shared__ int lstart[NBUCK], loff[NBUCK], runG[NBUCK];   // 9.4 KB
  const int c = blockIdx.x, tid = threadIdx.x;

  for (int i = tid; i < NBUCK; i += 512) {
    int st = (int)lscan[(size_t)c * NBUCK + i];
    lstart[i] = st;
    loff[i] = st;
    runG[i] = base[i] + (int)cscan[(size_t)c * NBUCK + i];
  }
  __syncthreads();

  // phase A: 3 wide loads per edge (2x dwordx4 + 1 dword over 36B)
  const int e0 = c * CHUNK_E;
  for (int e = e0 + tid; e < e0 + CHUNK_E; e += 512) {
    int r = row[e];
    const unsigned int* fp = (const unsigned int*)frames + (size_t)e * 9;
    uint4u qa = *(const uint4u*)fp;
    uint4u qb = *(const uint4u*)(fp + 4);
    unsigned int q8 = fp[8];
    unsigned int w0 = f2bf_bits(qa.x) | (f2bf_bits(qa.y) << 16);
    unsigned int w1 = f2bf_bits(qa.z) | (f2bf_bits(qa.w) << 16);
    unsigned int w2 = f2bf_bits(qb.x) | (f2bf_bits(qb.y) << 16);
    unsigned int w3 = f2bf_bits(qb.z) | (f2bf_bits(qb.w) << 16);
    unsigned int w4 = f2bf_bits(q8)   | ((unsigned)(r & 127) << 16);
    int b = r >> 7;
    int p = atomicAdd(&loff[b], 1);
    bkt[p] = (unsigned short)b;
    unsigned int* d = sbuf + p * 5;
    d[0] = w0; d[1] = w1; d[2] = w2; d[3] = w3; d[4] = w4;
  }
  __syncthreads();

  // phase B: flat dword copy — consecutive lanes -> consecutive global dwords
  for (int idx = tid; idx < CHUNK_E * 5; idx += 512) {
    unsigned int p = (unsigned int)idx / 5u;       // compiler: magic mul
    int k = idx - (int)p * 5;
    int b = bkt[p];
    int g = runG[b] + ((int)p - lstart[b]);
    payload[(size_t)g * 5 + k] = sbuf[idx];
  }
}

// ------- D: per-bucket (128-node) reduce — one-hot MFMA, zero atomics -------
__global__ __launch_bounds__(256) void reduce_kernel(const unsigned int* __restrict__ payload,
                                                     const int* __restrict__ base,
                                                     float* __restrict__ acc) {
  __shared__ unsigned short stg[2][16][RS];
  const int tid = threadIdx.x;
  const int b = blockIdx.x;
  const int wid = tid >> 6, lane = tid & 63;
  const int lr = lane & 15, lk = lane >> 4;

  for (int i = tid; i < RS; i += 256) {            // count row = 1.0 bf16
    stg[0][9][i] = 0x3F80; stg[1][9][i] = 0x3F80;
  }

  const int p0 = base[b], p1 = base[b + 1];
  const int nch = (p1 - p0 + CE - 1) / CE;
  const int s0 = wid * 2;
  const unsigned na = (unsigned)((s0 << 4) | lr);       // per-lane full-id consts
  const unsigned nbod = (unsigned)(((s0 + 1) << 4) | lr);

  f32x4 c0 = {0.f, 0.f, 0.f, 0.f};
  f32x4 c1 = {0.f, 0.f, 0.f, 0.f};

  auto STAGE = [&](int c, int buf) {
    int p = p0 + c * CE + tid;
    if (p < p1) {
      const unsigned int* s = payload + (size_t)p * 5;
      uint4u q = *(const uint4u*)s;                  // wide sequential load
      unsigned int w4 = s[4];
      stg[buf][0][tid] = (unsigned short)q.x;
      stg[buf][1][tid] = (unsigned short)(q.x >> 16);
      stg[buf][2][tid] = (unsigned short)q.y;
      stg[buf][3][tid] = (unsigned short)(q.y >> 16);
      stg[buf][4][tid] = (unsigned short)q.z;
      stg[buf][5][tid] = (unsigned short)(q.z >> 16);
      stg[buf][6][tid] = (unsigned short)q.w;
      stg[buf][7][tid] = (unsigned short)(q.w >> 16);
      stg[buf][8][tid] = (unsigned short)w4;
      stg[buf][10][tid] = (unsigned short)(w4 >> 16);
    } else {
#pragma unroll
      for (int k = 0; k < 9; ++k) stg[buf][k][tid] = 0;   // keep B finite
      stg[buf][10][tid] = 0xFFFF;                         // matches no id
    }
  };

  auto COMP = [&](int buf) {
#pragma unroll
    for (int g = 0; g < 8; ++g) {
      short8 bf = *(const short8*)&stg[buf][lr][g * 32 + lk * 8];
      short8 nv = *(const short8*)&stg[buf][10][g * 32 + lk * 8]; // broadcast
      short8 a0, a1;
#pragma unroll
      for (int j = 0; j < 8; ++j) {
        unsigned nid = (unsigned short)nv[j];
        a0[j] = (short)((nid == na)   ? 0x3F80 : 0);
        a1[j] = (short)((nid == nbod) ? 0x3F80 : 0);
      }
      c0 = __builtin_amdgcn_mfma_f32_16x16x32_bf16(a0, bf, c0, 0, 0, 0);
      c1 = __builtin_amdgcn_mfma_f32_16x16x32_bf16(a1, bf, c1, 0, 0, 0);
    }
  };

  if (nch > 0) {
    STAGE(0, 0);
    __syncthreads();
    for (int c = 0; c < nch; ++c) {
      if (c + 1 < nch) STAGE(c + 1, (c + 1) & 1);  // overlap with compute
      COMP(c & 1);
      __syncthreads();
    }
  }
  // writeout: D col = comp (lr), row = lk*4+j within subtile
  const int n0 = b << 7;
  if (lr < 10) {
#pragma unroll
    for (int j = 0; j < 4; ++j) {
      int r = lk * 4 + j;
      int x0 = n0 + s0 * 16 + r;
      int x1 = n0 + (s0 + 1) * 16 + r;
      if (x0 < N_NODES) acc[(size_t)x0 * 10 + lr] = c0[j];
      if (x1 < N_NODES) acc[(size_t)x1 * 10 + lr] = c1[j];
    }
  }
}

// ---------------- prep: pre-swizzle Ws/Wg into MFMA B-fragment layout -------
__global__ __launch_bounds__(256) void prep_kernel(const float* __restrict__ Ws,
                                                   const float* __restrict__ Wg,
                                                   unsigned short* __restrict__ wsWs,
                                                   unsigned short* __restrict__ wsWg) {
  int idx = blockIdx.x * 256 + threadIdx.x;     // 80 blocks -> 20480 threads
  if (idx < 8 * 5 * 512) {                      // ((nt*5+kk)*64 + l)*8 + j
    int j = idx & 7, l = (idx >> 3) & 63, t = idx >> 9;
    int nt = t / 5, kk = t - nt * 5;
    int o = nt * 16 + (l & 15);
    int m = kk * 32 + ((l >> 4) << 3) + j;
    wsWs[idx] = (m < 153) ? f2bf(Ws[o * 153 + m]) : (unsigned short)0;
  }
  if (idx < 4 * 512) {                          // ((kk*64 + l)*8 + j)
    int j = idx & 7, l = (idx >> 3) & 63, kk = idx >> 9;
    int v = l & 15;
    int m = kk * 32 + ((l >> 4) << 3) + j;
    wsWg[idx] = f2bf(Wg[v * 128 + m]);
  }
}

// ------- node phase: MFMA, 4 barriers/group, wave-redundant gate ------------
__global__ __launch_bounds__(256, 4) void node_kernel(
    const float* __restrict__ scalar_rep,   // [N][128]
    const float* __restrict__ vrep,         // [N][16][3]
    const float* __restrict__ Wd,           // [16][16]
    const float* __restrict__ Wf,           // [3][16]
    const float* __restrict__ bs,           // [128]
    const float* __restrict__ Wu,           // [16][16]
    const float* __restrict__ bg,           // [16]
    const unsigned short* __restrict__ wsWs,// pre-swizzled B-frags [8][5][64][8]
    const unsigned short* __restrict__ wsWg,// pre-swizzled B-frags [4][64][8]
    const float* __restrict__ acc,          // [N][10]
    float* __restrict__ out_s,              // [N][128]
    float* __restrict__ out_v) {            // [N][16][3]
  __shared__ alignas(16) unsigned short s_mergedb[16 * 168];  // bf16, pad->168
  __shared__ alignas(16) unsigned short s_sfb[16 * 136];      // bf16 silu
  __shared__ float s_vrep[16][48];
  __shared__ float s_vh[16][48];
  __shared__ float s_WdT[256], s_WuT[256], s_Wf[48], s_bs[128], s_bg[16];

  const int tid = threadIdx.x;
  {
    int a = tid >> 4, b = tid & 15;
    s_WdT[b * 16 + a] = Wd[tid];
    s_WuT[b * 16 + a] = Wu[tid];
  }
  if (tid < 48) s_Wf[tid] = Wf[tid];
  if (tid < 128) s_bs[tid] = bs[tid];
  if (tid < 16) s_bg[tid] = bg[tid];
  if (tid < 240) {                       // zero merged pad cols 153..167
    int r = tid / 15, c = 153 + tid % 15;
    s_mergedb[r * 168 + c] = 0;
  }

  const int i4 = tid >> 4, j4 = tid & 15;
  const int wid = tid >> 6, lane = tid & 63;
  const int lr = lane & 15, lk = lane >> 4;

  const float4* scalar4 = (const float4*)scalar_rep;
  const float4* vrep4 = (const float4*)vrep;

  for (int g = blockIdx.x; g < N_NODES / NB; g += gridDim.x) {
    const int n0 = g * NB;
    __syncthreads();   // (A) previous iteration consumers done
    // stage scalar_rep -> bf16 merged[.,0:128]
    for (int idx = tid; idx < 512; idx += 256) {
      float4 v = scalar4[(size_t)n0 * 32 + idx];
      int r = idx >> 5, c4 = idx & 31;
      unsigned short* d = s_mergedb + r * 168 + c4 * 4;
      d[0] = f2bf(v.x); d[1] = f2bf(v.y); d[2] = f2bf(v.z); d[3] = f2bf(v.w);
    }
    // stage vector_rep f32
    for (int idx = tid; idx < 192; idx += 256)
      ((float4*)s_vrep)[idx] = vrep4[(size_t)n0 * 12 + idx];
    __syncthreads();   // (B)
    // vh + vnorm
    {
      float a0 = 0.f, a1 = 0.f, a2 = 0.f;
#pragma unroll
      for (int v = 0; v < 16; ++v) {
        float w = s_WdT[v * 16 + j4];
        a0 += s_vrep[i4][v * 3 + 0] * w;
        a1 += s_vrep[i4][v * 3 + 1] * w;
        a2 += s_vrep[i4][v * 3 + 2] * w;
      }
      s_vh[i4][j4]      = a0;
      s_vh[i4][16 + j4] = a1;
      s_vh[i4][32 + j4] = a2;
      s_mergedb[i4 * 168 + 128 + j4] = f2bf(sqrtf(a0 * a0 + a1 * a1 + a2 * a2 + EPSV));
    }
    // fused vdf + scalar_hidden (registers only, no cross-thread handoff)
    if (j4 < 9) {
      int f = j4 / 3, s = j4 - f * 3;
      float vt0 = 0.f, vt1 = 0.f, vt2 = 0.f;
#pragma unroll
      for (int v = 0; v < 16; ++v) {
        float w = s_Wf[f * 16 + v];
        vt0 += s_vrep[i4][v * 3 + 0] * w;
        vt1 += s_vrep[i4][v * 3 + 1] * w;
        vt2 += s_vrep[i4][v * 3 + 2] * w;
      }
      const float* a = acc + (size_t)(n0 + i4) * 10;
      float cnum = fmaxf(a[9], 1.0f);
      float sum = a[s * 3 + 0] * vt0 + a[s * 3 + 1] * vt1 + a[s * 3 + 2] * vt2;
      s_mergedb[i4 * 168 + 144 + j4] = f2bf(sum / cnum);
    }
    __syncthreads();   // (C)
    // big MFMA: merged[16x160] @ WsT[160x128]; wave wid owns N-tiles 2w,2w+1
    {
      const int nt0 = wid * 2;
      short8 afrag[5];
#pragma unroll
      for (int kk = 0; kk < 5; ++kk)
        afrag[kk] = *(const short8*)(s_mergedb + lr * 168 + kk * 32 + lk * 8);
      float b0v = s_bs[nt0 * 16 + lr], b1v = s_bs[nt0 * 16 + 16 + lr];
      f32x4 acc0 = {b0v, b0v, b0v, b0v};
      f32x4 acc1 = {b1v, b1v, b1v, b1v};
#pragma unroll
      for (int kk = 0; kk < 5; ++kk) {
        short8 bf0 = *(const short8*)(wsWs + (((nt0 * 5 + kk) << 6) + lane) * 8);
        short8 bf1 = *(const short8*)(wsWs + ((((nt0 + 1) * 5 + kk) << 6) + lane) * 8);
        acc0 = __builtin_amdgcn_mfma_f32_16x16x32_bf16(afrag[kk], bf0, acc0, 0, 0, 0);
        acc1 = __builtin_amdgcn_mfma_f32_16x16x32_bf16(afrag[kk], bf1, acc1, 0, 0, 0);
      }
#pragma unroll
      for (int j = 0; j < 4; ++j) {
        int node = lk * 4 + j;
        float x0 = acc0[j];
        float sf0 = x0 / (1.0f + __expf(-x0));
        out_s[(size_t)(n0 + node) * 128 + nt0 * 16 + lr] = sf0;
        s_sfb[node * 136 + nt0 * 16 + lr] = f2bf(sf0);
        float x1 = acc1[j];
        float sf1 = x1 / (1.0f + __expf(-x1));
        out_s[(size_t)(n0 + node) * 128 + nt0 * 16 + 16 + lr] = sf1;
        s_sfb[node * 136 + nt0 * 16 + 16 + lr] = f2bf(sf1);
      }
    }
    __syncthreads();   // (D)
    // gate MFMA redundantly on ALL waves + shfl distribute + v_up (no barrier)
    {
      float gb = s_bg[lr];
      f32x4 gacc = {gb, gb, gb, gb};
#pragma unroll
      for (int kk = 0; kk < 4; ++kk) {
        short8 ga = *(const short8*)(s_sfb + lr * 136 + kk * 32 + lk * 8);
        short8 gw = *(const short8*)(wsWg + (((kk << 6) + lane) * 8));
        gacc = __builtin_amdgcn_mfma_f32_16x16x32_bf16(ga, gw, gacc, 0, 0, 0);
      }
      // lane l needs gate[row = wid*4 + (l>>4)][col = l&15]
      // source lane = wid*16 + (l&15), element j = l>>4
      int src = (wid << 4) | (lane & 15);
      float g0 = __shfl(gacc[0], src);
      float g1 = __shfl(gacc[1], src);
      float g2 = __shfl(gacc[2], src);
      float g3 = __shfl(gacc[3], src);
      int q = lane >> 4;
      float gv = (q == 0) ? g0 : (q == 1) ? g1 : (q == 2) ? g2 : g3;
      float gt = 1.0f / (1.0f + __expf(-gv));
      // v_up + gated output (thread (i4, j4); gate row i4 = wid*4+(lane>>4))
      float b0 = 0.f, b1 = 0.f, b2 = 0.f;
#pragma unroll
      for (int h = 0; h < 16; ++h) {
        float w = s_WuT[h * 16 + j4];
        b0 += s_vh[i4][h]      * w;
        b1 += s_vh[i4][16 + h] * w;
        b2 += s_vh[i4][32 + h] * w;
      }
      size_t basep = (size_t)(n0 + i4) * 48 + (size_t)j4 * 3;
      out_v[basep + 0] = b0 * gt;
      out_v[basep + 1] = b1 * gt;
      out_v[basep + 2] = b2 * gt;
    }
  }
}

extern "C" void kernel_launch(void* const* d_in, const int* in_sizes, int n_in,
                              void* d_out, int out_size, void* d_ws, size_t ws_size,
                              hipStream_t stream) {
  const float* scalar_rep = (const float*)d_in[0];
  const float* vector_rep = (const float*)d_in[1];
  const float* frames     = (const float*)d_in[2];
  const float* W_down     = (const float*)d_in[3];
  const float* W_frames   = (const float*)d_in[4];
  const float* W_scalar   = (const float*)d_in[5];
  const float* b_scalar   = (const float*)d_in[6];
  const float* W_up       = (const float*)d_in[7];
  const float* W_gate     = (const float*)d_in[8];
  const float* b_gate     = (const float*)d_in[9];
  const int*   edge_index = (const int*)d_in[10];   // [2][E], row = first E

  float* out = (float*)d_out;

  // workspace layout
  unsigned short* hist  = (unsigned short*)d_ws;            // 1280*782 u16
  unsigned short* lscan = hist  + (size_t)NCHUNK * NBUCK;   // 1280*782 u16
  unsigned short* cscan = lscan + (size_t)NCHUNK * NBUCK;   // 1280*782 u16
  int*   total   = (int*)(cscan + (size_t)NCHUNK * NBUCK);  // 800
  int*   base    = total + 800;                             // 800
  unsigned int* payload = (unsigned int*)(base + 800);      // 3.2M * 5 dw = 64MB
  float* acc     = (float*)(payload + 16000000);            // 1M floats
  unsigned short* wsWs = (unsigned short*)(acc + 1000000);  // 20480 bf16
  unsigned short* wsWg = wsWs + 20480;                      // 2048 bf16

  prep_kernel   <<<80,     256, 0, stream>>>(W_scalar, W_gate, wsWs, wsWg);
  hist_kernel   <<<NCHUNK, 256, 0, stream>>>(edge_index, hist, lscan);
  scanc_kernel  <<<NBUCK,  256, 0, stream>>>(hist, cscan, total);
  scanb_kernel  <<<1,      256, 0, stream>>>(total, base);
  scatter_kernel<<<NCHUNK, 512, 0, stream>>>(edge_index, lscan, cscan, base,
                                             frames, payload);
  reduce_kernel <<<NBUCK,  256, 0, stream>>>(payload, base, acc);

  node_kernel<<<1024, 256, 0, stream>>>(
      scalar_rep, vector_rep, W_down, W_frames, b_scalar,
      W_up, b_gate, wsWs, wsWg, acc,
      out, out + (size_t)N_NODES * 128);
}